// Round 1
// baseline (1133.031 us; speedup 1.0000x reference)
//
#include <hip/hip_runtime.h>
#include <hip/hip_bf16.h>
#include <math.h>

typedef __hip_bfloat16 bf16;
typedef __attribute__((ext_vector_type(8))) short short8;   // 8 bf16 = one MFMA A/B frag
typedef __attribute__((ext_vector_type(4))) float floatx4;  // MFMA C/D frag

constexpr int Bb = 4, Ss = 2048, Dd = 2048, Hh = 16, DKk = 128;

__device__ __forceinline__ void async_ld16(const bf16* g, bf16* l) {
    __builtin_amdgcn_global_load_lds(
        (__attribute__((address_space(1))) void*)g,
        (__attribute__((address_space(3))) void*)l, 16, 0, 0);
}

// ---------------- fp32 -> bf16 conversion (8 elems/thread) ----------------
__global__ void cvt_bf16(const float* __restrict__ in, bf16* __restrict__ out, int n8) {
    int i = blockIdx.x * 256 + threadIdx.x;
    if (i >= n8) return;
    const float4* p = (const float4*)in + 2 * (size_t)i;
    float4 a = p[0], b = p[1];
    float v[8] = {a.x, a.y, a.z, a.w, b.x, b.y, b.z, b.w};
    bf16 h[8];
#pragma unroll
    for (int j = 0; j < 8; j++) h[j] = __float2bfloat16(v[j]);
    __builtin_memcpy(out + 8 * (size_t)i, h, 16);
}

// ---------------- RoPE tables: tab[s*64+f] = (cos, sin) ----------------
__global__ void rope_tables(float2* __restrict__ tab) {
    int i = blockIdx.x * 256 + threadIdx.x;   // exactly S*64 threads
    int s = i >> 6, f = i & 63;
    float inv_freq = powf(10000.0f, -(float)(2 * f) / 128.0f);
    float ang = (float)s * inv_freq;
    tab[i] = make_float2(cosf(ang), sinf(ang));
}

// ---------------- bf16 GEMM: C[M,N] = A[M,K] * B[N,K]^T ----------------
// EPI=0: plain fp32 store to outF. EPI=1: qkv epilogue (RoPE + scatter to q/k/vT).
template <int EPI>
__global__ __launch_bounds__(256, 2)
void gemm_bf16(const bf16* __restrict__ A, const bf16* __restrict__ Bm,
               int N, int K,
               float* __restrict__ outF,
               bf16* __restrict__ qb, bf16* __restrict__ kb, bf16* __restrict__ vtb,
               const float2* __restrict__ rope) {
    __shared__ bf16 As[128 * 32];
    __shared__ bf16 Bs[128 * 32];
    const int tid = threadIdx.x;
    const int wave = tid >> 6, lane = tid & 63;
    const int quad = lane >> 4, l16 = lane & 15;
    const int wm = wave >> 1, wn = wave & 1;
    const int m0 = blockIdx.y * 128;
    const int n0 = blockIdx.x * 128;

    // staging: thread t loads 16B; tile row = li>>2, col = (li&3)*8 elems; li = round*256 + tid
    const int srow = tid >> 2;
    const int scol = (tid & 3) * 8;
    const bf16* ap0 = A  + (size_t)(m0 + srow) * K + scol;
    const bf16* ap1 = A  + (size_t)(m0 + 64 + srow) * K + scol;
    const bf16* bp0 = Bm + (size_t)(n0 + srow) * K + scol;
    const bf16* bp1 = Bm + (size_t)(n0 + 64 + srow) * K + scol;
    bf16* asd0 = As + wave * 512;          // LDS dest = wave-uniform base + lane*16B (HW)
    bf16* asd1 = As + 2048 + wave * 512;
    bf16* bsd0 = Bs + wave * 512;
    bf16* bsd1 = Bs + 2048 + wave * 512;

    floatx4 acc[4][4] = {};

    for (int k0 = 0; k0 < K; k0 += 32) {
        __syncthreads();
        async_ld16(ap0 + k0, asd0);
        async_ld16(ap1 + k0, asd1);
        async_ld16(bp0 + k0, bsd0);
        async_ld16(bp1 + k0, bsd1);
        __syncthreads();
        short8 af[4], bfr[4];
#pragma unroll
        for (int i = 0; i < 4; i++)
            af[i] = *(const short8*)(As + (wm * 64 + i * 16 + l16) * 32 + quad * 8);
#pragma unroll
        for (int j = 0; j < 4; j++)
            bfr[j] = *(const short8*)(Bs + (wn * 64 + j * 16 + l16) * 32 + quad * 8);
#pragma unroll
        for (int i = 0; i < 4; i++)
#pragma unroll
            for (int j = 0; j < 4; j++)
                acc[i][j] = __builtin_amdgcn_mfma_f32_16x16x32_bf16(af[i], bfr[j], acc[i][j], 0, 0, 0);
    }

    if (EPI == 0) {
#pragma unroll
        for (int i = 0; i < 4; i++) {
            const int gm0 = m0 + wm * 64 + i * 16 + quad * 4;
#pragma unroll
            for (int j = 0; j < 4; j++) {
                const int gn = n0 + wn * 64 + j * 16 + l16;
#pragma unroll
                for (int r = 0; r < 4; r++)
                    outF[(size_t)(gm0 + r) * N + gn] = acc[i][j][r];
            }
        }
    } else {
        // block covers exactly one (t, h): 2048%128==0, dk=128
        const int t = n0 >> 11;          // 0=q 1=k 2=v
        const int h = (n0 >> 7) & 15;
#pragma unroll
        for (int j = 0; j < 4; j++) {
            const int d = wn * 64 + j * 16 + l16;   // 0..127 within head
#pragma unroll
            for (int i = 0; i < 4; i++) {
#pragma unroll
                for (int r = 0; r < 4; r++) {
                    const int gm = m0 + wm * 64 + i * 16 + quad * 4 + r;
                    const int b = gm >> 11, s = gm & 2047;
                    const size_t bh = (size_t)(b * Hh + h);
                    float val = acc[i][j][r];
                    if (t < 2) {
                        // RoPE: pair (even,odd) d are adjacent lanes (d LSB == lane LSB)
                        float partner = __shfl_xor(val, 1, 64);
                        float2 cs = rope[s * 64 + (d >> 1)];
                        float nv = (d & 1) ? (val * cs.x + partner * cs.y)
                                           : (val * cs.x - partner * cs.y);
                        bf16 o = __float2bfloat16(nv);
                        if (t == 0) qb[(bh * Ss + s) * DKk + d] = o;
                        else        kb[(bh * Ss + s) * DKk + d] = o;
                    } else {
                        vtb[(bh * DKk + d) * Ss + s] = __float2bfloat16(val);  // V transposed
                    }
                }
            }
        }
    }
}

// ---------------- flash attention (causal, online softmax) ----------------
// grid (S/128, B*H); 4 waves x 32 q-rows. Q in regs, K/V frags from global (L2),
// P transposed C->A layout through per-wave-private LDS. No __syncthreads needed.
__global__ __launch_bounds__(256, 1)
void flash_attn(const bf16* __restrict__ q, const bf16* __restrict__ k,
                const bf16* __restrict__ vt, bf16* __restrict__ o) {
    __shared__ unsigned short Pl[4][32 * 128];
    const int tid = threadIdx.x, wave = tid >> 6, lane = tid & 63;
    const int quad = lane >> 4, l16 = lane & 15;
    const int bh = blockIdx.y;
    const int q0 = blockIdx.x * 128;
    const int qw0 = q0 + wave * 32;
    const bf16* qbp = q  + (size_t)bh * Ss * DKk;
    const bf16* kbp = k  + (size_t)bh * Ss * DKk;
    const bf16* vbp = vt + (size_t)bh * DKk * Ss;
    unsigned short* Pw = Pl[wave];

    short8 qf[2][4];
#pragma unroll
    for (int im = 0; im < 2; im++)
#pragma unroll
        for (int kk = 0; kk < 4; kk++)
            qf[im][kk] = *(const short8*)(qbp + (size_t)(qw0 + im * 16 + l16) * DKk + kk * 32 + quad * 8);

    floatx4 oacc[2][8] = {};
    float m_i[2][4], l_i[2][4];
#pragma unroll
    for (int im = 0; im < 2; im++)
#pragma unroll
        for (int r = 0; r < 4; r++) { m_i[im][r] = -__builtin_inff(); l_i[im][r] = 0.f; }

    const float scale = 0.08838834764831845f;  // 1/sqrt(128)

    for (int c0 = 0; c0 <= qw0 + 31; c0 += 128) {
        // S = Q K^T
        floatx4 sf[2][8] = {};
#pragma unroll
        for (int n = 0; n < 8; n++) {
            short8 kf[4];
#pragma unroll
            for (int kk = 0; kk < 4; kk++)
                kf[kk] = *(const short8*)(kbp + (size_t)(c0 + n * 16 + l16) * DKk + kk * 32 + quad * 8);
#pragma unroll
            for (int im = 0; im < 2; im++)
#pragma unroll
                for (int kk = 0; kk < 4; kk++)
                    sf[im][n] = __builtin_amdgcn_mfma_f32_16x16x32_bf16(qf[im][kk], kf[kk], sf[im][n], 0, 0, 0);
        }
        // scale + causal mask (col > row -> -inf)
#pragma unroll
        for (int im = 0; im < 2; im++)
#pragma unroll
            for (int n = 0; n < 8; n++) {
                const int col = c0 + n * 16 + l16;
#pragma unroll
                for (int r = 0; r < 4; r++) {
                    const int row = qw0 + im * 16 + quad * 4 + r;
                    float v = sf[im][n][r] * scale;
                    sf[im][n][r] = (col > row) ? -__builtin_inff() : v;
                }
            }
        // online softmax per row (row state: 16-lane col group reduction)
#pragma unroll
        for (int im = 0; im < 2; im++)
#pragma unroll
            for (int r = 0; r < 4; r++) {
                float mx = sf[im][0][r];
#pragma unroll
                for (int n = 1; n < 8; n++) mx = fmaxf(mx, sf[im][n][r]);
#pragma unroll
                for (int off = 1; off < 16; off <<= 1)
                    mx = fmaxf(mx, __shfl_xor(mx, off, 64));
                const float mnew = fmaxf(m_i[im][r], mx);
                const float alpha = __expf(m_i[im][r] - mnew);
                m_i[im][r] = mnew;
                float rs = 0.f;
                const int prow = (im * 16 + quad * 4 + r) * 128;
#pragma unroll
                for (int n = 0; n < 8; n++) {
                    float p = __expf(sf[im][n][r] - mnew);
                    rs += p;
                    bf16 pb = __float2bfloat16(p);
                    unsigned short bits;
                    __builtin_memcpy(&bits, &pb, 2);
                    Pw[prow + n * 16 + l16] = bits;
                }
#pragma unroll
                for (int off = 1; off < 16; off <<= 1) rs += __shfl_xor(rs, off, 64);
                l_i[im][r] = l_i[im][r] * alpha + rs;
#pragma unroll
                for (int n2 = 0; n2 < 8; n2++) oacc[im][n2][r] *= alpha;
            }
        // O += P V   (P via LDS transpose to A-layout; V^T frags from global)
#pragma unroll
        for (int kk = 0; kk < 4; kk++) {
            short8 pf[2];
#pragma unroll
            for (int im = 0; im < 2; im++)
                pf[im] = *(const short8*)(Pw + (im * 16 + l16) * 128 + kk * 32 + quad * 8);
#pragma unroll
            for (int n2 = 0; n2 < 8; n2++) {
                short8 vf = *(const short8*)(vbp + (size_t)(n2 * 16 + l16) * Ss + c0 + kk * 32 + quad * 8);
#pragma unroll
                for (int im = 0; im < 2; im++)
                    oacc[im][n2] = __builtin_amdgcn_mfma_f32_16x16x32_bf16(pf[im], vf, oacc[im][n2], 0, 0, 0);
            }
        }
    }
    // epilogue: normalize, store to [B,S,H*dk] bf16
    const int b = bh >> 4, h = bh & 15;
#pragma unroll
    for (int im = 0; im < 2; im++)
#pragma unroll
        for (int r = 0; r < 4; r++) {
            const float inv = 1.0f / l_i[im][r];
            const int s = qw0 + im * 16 + quad * 4 + r;
#pragma unroll
            for (int n2 = 0; n2 < 8; n2++) {
                const int d = n2 * 16 + l16;
                o[((size_t)(b * Ss + s)) * Dd + h * 128 + d] =
                    __float2bfloat16(oacc[im][n2][r] * inv);
            }
        }
}

extern "C" void kernel_launch(void* const* d_in, const int* in_sizes, int n_in,
                              void* d_out, int out_size, void* d_ws, size_t ws_size,
                              hipStream_t stream) {
    const float* x     = (const float*)d_in[0];
    const float* w_qkv = (const float*)d_in[1];
    const float* w_out = (const float*)d_in[2];
    float* out = (float*)d_out;
    char* ws = (char*)d_ws;

    // workspace carve (total 168,820,736 B ~ 161 MiB)
    bf16*   xb  = (bf16*)(ws);                 // 32 MiB  x bf16; reused as attn output
    bf16*   wqb = (bf16*)(ws + 33554432);      // 24 MiB  w_qkv bf16
    bf16*   wob = (bf16*)(ws + 58720256);      //  8 MiB  w_out bf16
    bf16*   qb  = (bf16*)(ws + 67108864);      // 32 MiB  q   [B,H,S,dk]
    bf16*   kb  = (bf16*)(ws + 100663296);     // 32 MiB  k   [B,H,S,dk]
    bf16*   vtb = (bf16*)(ws + 134217728);     // 32 MiB  v^T [B,H,dk,S]
    float2* rt  = (float2*)(ws + 167772160);   //  1 MiB  rope tables

    cvt_bf16<<<8192, 256, 0, stream>>>(x, xb, 2097152);
    cvt_bf16<<<6144, 256, 0, stream>>>(w_qkv, wqb, 1572864);
    cvt_bf16<<<2048, 256, 0, stream>>>(w_out, wob, 524288);
    rope_tables<<<512, 256, 0, stream>>>(rt);

    // qkv = x @ w_qkv^T, fused RoPE + scatter
    gemm_bf16<1><<<dim3(48, 64), 256, 0, stream>>>(xb, wqb, 6144, 2048,
                                                   nullptr, qb, kb, vtb, rt);
    // attention -> xb (reused as [B,S,D] bf16)
    flash_attn<<<dim3(16, 64), 256, 0, stream>>>(qb, kb, vtb, xb);
    // out = attn @ w_out^T
    gemm_bf16<0><<<dim3(16, 64), 256, 0, stream>>>(xb, wob, 2048, 2048,
                                                   out, nullptr, nullptr, nullptr, rt);
}

// Round 2
// 775.806 us; speedup vs baseline: 1.4605x; 1.4605x over previous
//
#include <hip/hip_runtime.h>
#include <hip/hip_bf16.h>
#include <math.h>

typedef __hip_bfloat16 bf16;
typedef __attribute__((ext_vector_type(8))) short short8;   // 8 bf16 = one MFMA A/B frag
typedef __attribute__((ext_vector_type(4))) float floatx4;  // MFMA C/D frag

constexpr int Bb = 4, Ss = 2048, Dd = 2048, Hh = 16, DKk = 128;

__device__ __forceinline__ void async_ld16(const bf16* g, bf16* l) {
    __builtin_amdgcn_global_load_lds(
        (__attribute__((address_space(1))) void*)g,
        (__attribute__((address_space(3))) void*)l, 16, 0, 0);
}

__device__ __forceinline__ unsigned int pk2(float a, float b) {
    bf16 ha = __float2bfloat16(a), hb = __float2bfloat16(b);
    unsigned short ua, ub;
    __builtin_memcpy(&ua, &ha, 2);
    __builtin_memcpy(&ub, &hb, 2);
    return (unsigned int)ua | ((unsigned int)ub << 16);
}

// ---------------- fp32 -> bf16 conversion (8 elems/thread) ----------------
__global__ void cvt_bf16(const float* __restrict__ in, bf16* __restrict__ out, int n8) {
    int i = blockIdx.x * 256 + threadIdx.x;
    if (i >= n8) return;
    const float4* p = (const float4*)in + 2 * (size_t)i;
    float4 a = p[0], b = p[1];
    float v[8] = {a.x, a.y, a.z, a.w, b.x, b.y, b.z, b.w};
    bf16 h[8];
#pragma unroll
    for (int j = 0; j < 8; j++) h[j] = __float2bfloat16(v[j]);
    __builtin_memcpy(out + 8 * (size_t)i, h, 16);
}

// ---------------- RoPE tables: tab[s*64+f] = (cos, sin) ----------------
__global__ void rope_tables(float2* __restrict__ tab) {
    int i = blockIdx.x * 256 + threadIdx.x;   // exactly S*64 threads
    int s = i >> 6, f = i & 63;
    float inv_freq = powf(10000.0f, -(float)(2 * f) / 128.0f);
    float ang = (float)s * inv_freq;
    tab[i] = make_float2(cosf(ang), sinf(ang));
}

// ---------------- bf16 GEMM: C[M,N] = A[M,K] * B[N,K]^T ----------------
template <int EPI>
__global__ __launch_bounds__(256, 2)
void gemm_bf16(const bf16* __restrict__ A, const bf16* __restrict__ Bm,
               int N, int K,
               float* __restrict__ outF,
               bf16* __restrict__ qb, bf16* __restrict__ kb, bf16* __restrict__ vtb,
               const float2* __restrict__ rope) {
    __shared__ bf16 As[128 * 32];
    __shared__ bf16 Bs[128 * 32];
    const int tid = threadIdx.x;
    const int wave = tid >> 6, lane = tid & 63;
    const int quad = lane >> 4, l16 = lane & 15;
    const int wm = wave >> 1, wn = wave & 1;
    const int m0 = blockIdx.y * 128;
    const int n0 = blockIdx.x * 128;

    const int srow = tid >> 2;
    const int scol = (tid & 3) * 8;
    const bf16* ap0 = A  + (size_t)(m0 + srow) * K + scol;
    const bf16* ap1 = A  + (size_t)(m0 + 64 + srow) * K + scol;
    const bf16* bp0 = Bm + (size_t)(n0 + srow) * K + scol;
    const bf16* bp1 = Bm + (size_t)(n0 + 64 + srow) * K + scol;
    bf16* asd0 = As + wave * 512;
    bf16* asd1 = As + 2048 + wave * 512;
    bf16* bsd0 = Bs + wave * 512;
    bf16* bsd1 = Bs + 2048 + wave * 512;

    floatx4 acc[4][4] = {};

    for (int k0 = 0; k0 < K; k0 += 32) {
        __syncthreads();
        async_ld16(ap0 + k0, asd0);
        async_ld16(ap1 + k0, asd1);
        async_ld16(bp0 + k0, bsd0);
        async_ld16(bp1 + k0, bsd1);
        __syncthreads();
        short8 af[4], bfr[4];
#pragma unroll
        for (int i = 0; i < 4; i++)
            af[i] = *(const short8*)(As + (wm * 64 + i * 16 + l16) * 32 + quad * 8);
#pragma unroll
        for (int j = 0; j < 4; j++)
            bfr[j] = *(const short8*)(Bs + (wn * 64 + j * 16 + l16) * 32 + quad * 8);
#pragma unroll
        for (int i = 0; i < 4; i++)
#pragma unroll
            for (int j = 0; j < 4; j++)
                acc[i][j] = __builtin_amdgcn_mfma_f32_16x16x32_bf16(af[i], bfr[j], acc[i][j], 0, 0, 0);
    }

    if (EPI == 0) {
#pragma unroll
        for (int i = 0; i < 4; i++) {
            const int gm0 = m0 + wm * 64 + i * 16 + quad * 4;
#pragma unroll
            for (int j = 0; j < 4; j++) {
                const int gn = n0 + wn * 64 + j * 16 + l16;
#pragma unroll
                for (int r = 0; r < 4; r++)
                    outF[(size_t)(gm0 + r) * N + gn] = acc[i][j][r];
            }
        }
    } else {
        const int t = n0 >> 11;          // 0=q 1=k 2=v
        const int h = (n0 >> 7) & 15;
#pragma unroll
        for (int j = 0; j < 4; j++) {
            const int d = wn * 64 + j * 16 + l16;
#pragma unroll
            for (int i = 0; i < 4; i++) {
#pragma unroll
                for (int r = 0; r < 4; r++) {
                    const int gm = m0 + wm * 64 + i * 16 + quad * 4 + r;
                    const int b = gm >> 11, s = gm & 2047;
                    const size_t bh = (size_t)(b * Hh + h);
                    float val = acc[i][j][r];
                    if (t < 2) {
                        float partner = __shfl_xor(val, 1, 64);
                        float2 cs = rope[s * 64 + (d >> 1)];
                        float nv = (d & 1) ? (val * cs.x + partner * cs.y)
                                           : (val * cs.x - partner * cs.y);
                        bf16 oo = __float2bfloat16(nv);
                        if (t == 0) qb[(bh * Ss + s) * DKk + d] = oo;
                        else        kb[(bh * Ss + s) * DKk + d] = oo;
                    } else {
                        vtb[(bh * DKk + d) * Ss + s] = __float2bfloat16(val);
                    }
                }
            }
        }
    }
}

// ---------------- flash attention v2 (St = K Q^T form, LDS-staged K/V) ----
// grid (S/128, B*H) with reversed x (long blocks first); 4 waves x 32 q-rows.
// K-tile & V^T-tile staged via global_load_lds (XOR column swizzle vs bank
// conflicts, swizzle applied at the DMA *source* so LDS dest stays linear).
// S^T = K.Q^T -> softmax state per l16 lane -> P^T B-frags via 8 shfls ->
// O^T = V^T.P^T. No P round-trip through LDS, no per-use global latency.
__global__ __launch_bounds__(256, 2)
void flash_attn(const bf16* __restrict__ q, const bf16* __restrict__ k,
                const bf16* __restrict__ vt, bf16* __restrict__ o) {
    __shared__ bf16 Ks[128 * 128];   // 32 KB  rows=kv, cols=d (chunks swizzled)
    __shared__ bf16 Vs[128 * 128];   // 32 KB  rows=d,  cols=kv (chunks swizzled)
    const int tid = threadIdx.x, wave = tid >> 6, lane = tid & 63;
    const int quad = lane >> 4, l16 = lane & 15;
    const int bh = blockIdx.y;
    const int xq = (int)gridDim.x - 1 - (int)blockIdx.x;   // long blocks first
    const int qw0 = xq * 128 + wave * 32;
    const bf16* qbp = q  + (size_t)bh * Ss * DKk;
    const bf16* kbp = k  + (size_t)bh * Ss * DKk;
    const bf16* vbp = vt + (size_t)bh * DKk * Ss;

    // Q as B-operand: B[n=q(l16)][k=d(quad*8+j)]
    short8 qB[2][4];
#pragma unroll
    for (int qf = 0; qf < 2; qf++)
#pragma unroll
        for (int kk = 0; kk < 4; kk++)
            qB[qf][kk] = *(const short8*)(qbp + (size_t)(qw0 + qf * 16 + l16) * DKk + kk * 32 + quad * 8);

    floatx4 oacc[8][2] = {};                 // O^T: [d-frag][q-frag]
    float m_i[2] = {-__builtin_inff(), -__builtin_inff()};
    float l_i[2] = {0.f, 0.f};
    const float scale = 0.08838834764831845f;  // 1/sqrt(128)
    const int ntiles = xq + 1;

    // staging geometry: thread stages 16B; row = r*16 + (tid>>4); stored chunk
    // = tid&15 holds global chunk (tid&15)^(row&7)  (row&7 == (tid>>4)&7)
    const int srow = tid >> 4;
    const int chunkg = (tid & 15) ^ (srow & 7);
    const int swz = (l16 & 7);               // read-side swizzle

    for (int it = 0; it < ntiles; ++it) {
        const int c0 = it * 128;
        __syncthreads();
#pragma unroll
        for (int r = 0; r < 8; r++) {
            async_ld16(kbp + (size_t)(c0 + r * 16 + srow) * DKk + chunkg * 8,
                       Ks + ((r * 256 + tid) << 3));
            async_ld16(vbp + (size_t)(r * 16 + srow) * Ss + c0 + chunkg * 8,
                       Vs + ((r * 256 + tid) << 3));
        }
        __syncthreads();

        const int kvmax = min(127, qw0 + 31 - c0);
        const int lim_n = (kvmax >> 4) + 1;     // always even: 2,4,6,8
        const int lim_k = lim_n >> 1;

        // ---- S^T = K Q^T ----
        floatx4 sf[8][2];
#pragma unroll
        for (int n = 0; n < 8; n++) {
            if (n < lim_n) {
                short8 kf[4];
#pragma unroll
                for (int kk = 0; kk < 4; kk++)
                    kf[kk] = *(const short8*)(Ks + (n * 16 + l16) * 128 + (((kk * 4 + quad) ^ swz) * 8));
                sf[n][0] = (floatx4){0.f, 0.f, 0.f, 0.f};
                sf[n][1] = (floatx4){0.f, 0.f, 0.f, 0.f};
#pragma unroll
                for (int kk = 0; kk < 4; kk++) {
                    sf[n][0] = __builtin_amdgcn_mfma_f32_16x16x32_bf16(kf[kk], qB[0][kk], sf[n][0], 0, 0, 0);
                    sf[n][1] = __builtin_amdgcn_mfma_f32_16x16x32_bf16(kf[kk], qB[1][kk], sf[n][1], 0, 0, 0);
                }
            }
        }

        // ---- online softmax (state per l16 lane, replicated across quads) ----
        unsigned int pp01[8][2], pp23[8][2];
#pragma unroll
        for (int qf = 0; qf < 2; qf++) {
            const int qrow = qw0 + qf * 16 + l16;
            float mx = -__builtin_inff();
#pragma unroll
            for (int n = 0; n < 8; n++) {
                if (n < lim_n) {
                    const int kvb = c0 + n * 16 + quad * 4;
#pragma unroll
                    for (int r = 0; r < 4; r++) {
                        float v = sf[n][qf][r] * scale;
                        v = (kvb + r > qrow) ? -__builtin_inff() : v;
                        sf[n][qf][r] = v;
                        mx = fmaxf(mx, v);
                    }
                }
            }
            mx = fmaxf(mx, __shfl_xor(mx, 16, 64));
            mx = fmaxf(mx, __shfl_xor(mx, 32, 64));
            const float mnew = fmaxf(m_i[qf], mx);
            const float alpha = __expf(m_i[qf] - mnew);
            m_i[qf] = mnew;
            float rs = 0.f;
#pragma unroll
            for (int n = 0; n < 8; n++) {
                if (n < lim_n) {
                    float p0 = __expf(sf[n][qf][0] - mnew);
                    float p1 = __expf(sf[n][qf][1] - mnew);
                    float p2 = __expf(sf[n][qf][2] - mnew);
                    float p3 = __expf(sf[n][qf][3] - mnew);
                    rs += (p0 + p1) + (p2 + p3);
                    pp01[n][qf] = pk2(p0, p1);
                    pp23[n][qf] = pk2(p2, p3);
                }
            }
            rs += __shfl_xor(rs, 16, 64);
            rs += __shfl_xor(rs, 32, 64);
            l_i[qf] = l_i[qf] * alpha + rs;
#pragma unroll
            for (int md = 0; md < 8; md++)
#pragma unroll
                for (int r = 0; r < 4; r++) oacc[md][qf][r] *= alpha;
        }

        // ---- O^T += V^T P^T ----
        const int srcA = ((quad & 1) * 2) * 16 + l16;   // j<4 source lane
        const int srcB = srcA + 16;                      // j>=4 source lane
#pragma unroll
        for (int kv = 0; kv < 4; kv++) {
            if (kv < lim_k) {
                short8 pB[2];
#pragma unroll
                for (int qf = 0; qf < 2; qf++) {
                    unsigned int a01 = (unsigned int)__shfl((int)pp01[2 * kv][qf], srcA, 64);
                    unsigned int a23 = (unsigned int)__shfl((int)pp23[2 * kv][qf], srcA, 64);
                    unsigned int a45 = (unsigned int)__shfl((int)pp01[2 * kv][qf], srcB, 64);
                    unsigned int a67 = (unsigned int)__shfl((int)pp23[2 * kv][qf], srcB, 64);
                    unsigned int b01 = (unsigned int)__shfl((int)pp01[2 * kv + 1][qf], srcA, 64);
                    unsigned int b23 = (unsigned int)__shfl((int)pp23[2 * kv + 1][qf], srcA, 64);
                    unsigned int b45 = (unsigned int)__shfl((int)pp01[2 * kv + 1][qf], srcB, 64);
                    unsigned int b67 = (unsigned int)__shfl((int)pp23[2 * kv + 1][qf], srcB, 64);
                    const bool hi = quad >= 2;
                    unsigned int e[4];
                    e[0] = hi ? b01 : a01;
                    e[1] = hi ? b23 : a23;
                    e[2] = hi ? b45 : a45;
                    e[3] = hi ? b67 : a67;
                    __builtin_memcpy(&pB[qf], e, 16);
                }
#pragma unroll
                for (int md = 0; md < 8; md++) {
                    short8 vf = *(const short8*)(Vs + (md * 16 + l16) * 128 + (((kv * 4 + quad) ^ swz) * 8));
                    oacc[md][0] = __builtin_amdgcn_mfma_f32_16x16x32_bf16(vf, pB[0], oacc[md][0], 0, 0, 0);
                    oacc[md][1] = __builtin_amdgcn_mfma_f32_16x16x32_bf16(vf, pB[1], oacc[md][1], 0, 0, 0);
                }
            }
        }
    }

    // ---- epilogue: O^T (d=md*16+quad*4+r, s=qw0+qf*16+l16) -> [B,S,D] bf16 ----
    const int b = bh >> 4, h = bh & 15;
#pragma unroll
    for (int qf = 0; qf < 2; qf++) {
        const float inv = 1.0f / l_i[qf];
        const int s = qw0 + qf * 16 + l16;
        bf16* orow = o + (size_t)(b * Ss + s) * Dd + h * 128;
#pragma unroll
        for (int md = 0; md < 8; md++) {
            unsigned int w[2];
            w[0] = pk2(oacc[md][qf][0] * inv, oacc[md][qf][1] * inv);
            w[1] = pk2(oacc[md][qf][2] * inv, oacc[md][qf][3] * inv);
            __builtin_memcpy(orow + md * 16 + quad * 4, w, 8);
        }
    }
}

extern "C" void kernel_launch(void* const* d_in, const int* in_sizes, int n_in,
                              void* d_out, int out_size, void* d_ws, size_t ws_size,
                              hipStream_t stream) {
    const float* x     = (const float*)d_in[0];
    const float* w_qkv = (const float*)d_in[1];
    const float* w_out = (const float*)d_in[2];
    float* out = (float*)d_out;
    char* ws = (char*)d_ws;

    bf16*   xb  = (bf16*)(ws);                 // 32 MiB  x bf16; reused as attn output
    bf16*   wqb = (bf16*)(ws + 33554432);      // 24 MiB  w_qkv bf16
    bf16*   wob = (bf16*)(ws + 58720256);      //  8 MiB  w_out bf16
    bf16*   qb  = (bf16*)(ws + 67108864);      // 32 MiB  q   [B,H,S,dk]
    bf16*   kb  = (bf16*)(ws + 100663296);     // 32 MiB  k   [B,H,S,dk]
    bf16*   vtb = (bf16*)(ws + 134217728);     // 32 MiB  v^T [B,H,dk,S]
    float2* rt  = (float2*)(ws + 167772160);   //  1 MiB  rope tables

    cvt_bf16<<<8192, 256, 0, stream>>>(x, xb, 2097152);
    cvt_bf16<<<6144, 256, 0, stream>>>(w_qkv, wqb, 1572864);
    cvt_bf16<<<2048, 256, 0, stream>>>(w_out, wob, 524288);
    rope_tables<<<512, 256, 0, stream>>>(rt);

    gemm_bf16<1><<<dim3(48, 64), 256, 0, stream>>>(xb, wqb, 6144, 2048,
                                                   nullptr, qb, kb, vtb, rt);
    flash_attn<<<dim3(16, 64), 256, 0, stream>>>(qb, kb, vtb, xb);
    gemm_bf16<0><<<dim3(16, 64), 256, 0, stream>>>(xb, wob, 2048, 2048,
                                                   out, nullptr, nullptr, nullptr, rt);
}

// Round 3
// 681.953 us; speedup vs baseline: 1.6615x; 1.1376x over previous
//
#include <hip/hip_runtime.h>
#include <hip/hip_bf16.h>
#include <math.h>

typedef __hip_bfloat16 bf16;
typedef __attribute__((ext_vector_type(8))) short short8;   // 8 bf16 = one MFMA A/B frag
typedef __attribute__((ext_vector_type(4))) float floatx4;  // MFMA C/D frag

constexpr int Bb = 4, Ss = 2048, Dd = 2048, Hh = 16, DKk = 128;

__device__ __forceinline__ void async_ld16(const bf16* g, bf16* l) {
    __builtin_amdgcn_global_load_lds(
        (__attribute__((address_space(1))) void*)g,
        (__attribute__((address_space(3))) void*)l, 16, 0, 0);
}

__device__ __forceinline__ unsigned int pk2(float a, float b) {
    bf16 ha = __float2bfloat16(a), hb = __float2bfloat16(b);
    unsigned short ua, ub;
    __builtin_memcpy(&ua, &ha, 2);
    __builtin_memcpy(&ub, &hb, 2);
    return (unsigned int)ua | ((unsigned int)ub << 16);
}

// ---------------- fp32 -> bf16 conversion (8 elems/thread) ----------------
__global__ void cvt_bf16(const float* __restrict__ in, bf16* __restrict__ out, int n8) {
    int i = blockIdx.x * 256 + threadIdx.x;
    if (i >= n8) return;
    const float4* p = (const float4*)in + 2 * (size_t)i;
    float4 a = p[0], b = p[1];
    float v[8] = {a.x, a.y, a.z, a.w, b.x, b.y, b.z, b.w};
    bf16 h[8];
#pragma unroll
    for (int j = 0; j < 8; j++) h[j] = __float2bfloat16(v[j]);
    __builtin_memcpy(out + 8 * (size_t)i, h, 16);
}

// ---------------- RoPE tables: tab[s*64+f] = (cos, sin) ----------------
__global__ void rope_tables(float2* __restrict__ tab) {
    int i = blockIdx.x * 256 + threadIdx.x;   // exactly S*64 threads
    int s = i >> 6, f = i & 63;
    float inv_freq = powf(10000.0f, -(float)(2 * f) / 128.0f);
    float ang = (float)s * inv_freq;
    tab[i] = make_float2(cosf(ang), sinf(ang));
}

// ---------------- bf16 GEMM: C[M,N] = A[M,K] * B[N,K]^T ----------------
// BK=64; LDS rows are 128 B (8 x 16-B chunks) with XOR-8 swizzle
// (pos = chunk ^ (row&7)) applied at the DMA SOURCE so the global_load_lds
// destination stays linear. Frag reads then hit each bank <=2-way (free).
template <int EPI>
__global__ __launch_bounds__(256, 2)
void gemm_bf16(const bf16* __restrict__ A, const bf16* __restrict__ Bm,
               int N, int K,
               float* __restrict__ outF,
               bf16* __restrict__ qb, bf16* __restrict__ kb, bf16* __restrict__ vtb,
               const float2* __restrict__ rope) {
    __shared__ bf16 As[128 * 64];   // 16 KB
    __shared__ bf16 Bs[128 * 64];   // 16 KB
    const int tid = threadIdx.x;
    const int wave = tid >> 6, lane = tid & 63;
    const int quad = lane >> 4, l16 = lane & 15;
    const int wm = wave >> 1, wn = wave & 1;
    const int m0 = blockIdx.y * 128;
    const int n0 = blockIdx.x * 128;

    // staging: thread loads 16 B; round r covers rows r*32 .. r*32+31
    const int srow = tid >> 3;                      // 0..31
    const int schunk = (tid & 7) ^ (srow & 7);      // swizzled source chunk
    const bf16* apr[4];
    const bf16* bpr[4];
#pragma unroll
    for (int r = 0; r < 4; r++) {
        apr[r] = A  + (size_t)(m0 + r * 32 + srow) * K + schunk * 8;
        bpr[r] = Bm + (size_t)(n0 + r * 32 + srow) * K + schunk * 8;
    }
    bf16* asd = As + tid * 8;   // + r*2048 elements per round (linear dest)
    bf16* bsd = Bs + tid * 8;

    floatx4 acc[4][4] = {};
    const int swz = l16 & 7;

    for (int k0 = 0; k0 < K; k0 += 64) {
        __syncthreads();
#pragma unroll
        for (int r = 0; r < 4; r++) {
            async_ld16(apr[r] + k0, asd + r * 2048);
            async_ld16(bpr[r] + k0, bsd + r * 2048);
        }
        __syncthreads();
#pragma unroll
        for (int kk = 0; kk < 2; kk++) {
            short8 af[4], bfr[4];
#pragma unroll
            for (int i = 0; i < 4; i++)
                af[i] = *(const short8*)(As + (wm * 64 + i * 16 + l16) * 64 + (((kk * 4 + quad) ^ swz) * 8));
#pragma unroll
            for (int j = 0; j < 4; j++)
                bfr[j] = *(const short8*)(Bs + (wn * 64 + j * 16 + l16) * 64 + (((kk * 4 + quad) ^ swz) * 8));
#pragma unroll
            for (int i = 0; i < 4; i++)
#pragma unroll
                for (int j = 0; j < 4; j++)
                    acc[i][j] = __builtin_amdgcn_mfma_f32_16x16x32_bf16(af[i], bfr[j], acc[i][j], 0, 0, 0);
        }
    }

    if (EPI == 0) {
#pragma unroll
        for (int i = 0; i < 4; i++) {
            const int gm0 = m0 + wm * 64 + i * 16 + quad * 4;
#pragma unroll
            for (int j = 0; j < 4; j++) {
                const int gn = n0 + wn * 64 + j * 16 + l16;
#pragma unroll
                for (int r = 0; r < 4; r++)
                    outF[(size_t)(gm0 + r) * N + gn] = acc[i][j][r];
            }
        }
    } else {
        const int t = n0 >> 11;          // 0=q 1=k 2=v
        const int h = (n0 >> 7) & 15;
        // fold softmax scale (and log2e for exp2-based softmax) into q
        const float qscale = 0.08838834764831845f * 1.442695040888963f;
        if (t < 2) {
#pragma unroll
            for (int j = 0; j < 4; j++) {
                const int d = wn * 64 + j * 16 + l16;
#pragma unroll
                for (int i = 0; i < 4; i++) {
#pragma unroll
                    for (int r = 0; r < 4; r++) {
                        const int gm = m0 + wm * 64 + i * 16 + quad * 4 + r;
                        const int b = gm >> 11, s = gm & 2047;
                        const size_t bh = (size_t)(b * Hh + h);
                        float val = acc[i][j][r];
                        float partner = __shfl_xor(val, 1, 64);
                        float2 cs = rope[s * 64 + (d >> 1)];
                        float nv = (d & 1) ? (val * cs.x + partner * cs.y)
                                           : (val * cs.x - partner * cs.y);
                        if (t == 0) {
                            qb[(bh * Ss + s) * DKk + d] = __float2bfloat16(nv * qscale);
                        } else {
                            kb[(bh * Ss + s) * DKk + d] = __float2bfloat16(nv);
                        }
                    }
                }
            }
        } else {
            // v: packed 8-B stores, 4 contiguous s per store
#pragma unroll
            for (int j = 0; j < 4; j++) {
                const int d = wn * 64 + j * 16 + l16;
#pragma unroll
                for (int i = 0; i < 4; i++) {
                    const int gm = m0 + wm * 64 + i * 16 + quad * 4;
                    const int b = gm >> 11, s = gm & 2047;
                    const size_t bh = (size_t)(b * Hh + h);
                    unsigned int w[2];
                    w[0] = pk2(acc[i][j][0], acc[i][j][1]);
                    w[1] = pk2(acc[i][j][2], acc[i][j][3]);
                    __builtin_memcpy(vtb + (bh * DKk + d) * Ss + s, w, 8);
                }
            }
        }
    }
}

// ---------------- flash attention (St = K Q^T form, LDS-staged K/V) -------
// q arrives pre-scaled by (1/sqrt(dk))*log2(e) -> softmax uses native exp2.
__global__ __launch_bounds__(256, 2)
void flash_attn(const bf16* __restrict__ q, const bf16* __restrict__ k,
                const bf16* __restrict__ vt, bf16* __restrict__ o) {
    __shared__ bf16 Ks[128 * 128];   // 32 KB  rows=kv, cols=d (chunks swizzled)
    __shared__ bf16 Vs[128 * 128];   // 32 KB  rows=d,  cols=kv (chunks swizzled)
    const int tid = threadIdx.x, wave = tid >> 6, lane = tid & 63;
    const int quad = lane >> 4, l16 = lane & 15;
    const int bh = blockIdx.y;
    const int xq = (int)gridDim.x - 1 - (int)blockIdx.x;   // long blocks first
    const int qw0 = xq * 128 + wave * 32;
    const bf16* qbp = q  + (size_t)bh * Ss * DKk;
    const bf16* kbp = k  + (size_t)bh * Ss * DKk;
    const bf16* vbp = vt + (size_t)bh * DKk * Ss;

    // Q as B-operand: B[n=q(l16)][k=d(quad*8+j)]
    short8 qB[2][4];
#pragma unroll
    for (int qf = 0; qf < 2; qf++)
#pragma unroll
        for (int kk = 0; kk < 4; kk++)
            qB[qf][kk] = *(const short8*)(qbp + (size_t)(qw0 + qf * 16 + l16) * DKk + kk * 32 + quad * 8);

    floatx4 oacc[8][2] = {};                 // O^T: [d-frag][q-frag]
    float m_i[2] = {-__builtin_inff(), -__builtin_inff()};
    float l_i[2] = {0.f, 0.f};
    const int ntiles = xq + 1;

    // staging geometry: thread stages 16B; row = r*16 + (tid>>4); stored chunk
    // = tid&15 holds global chunk (tid&15)^(row&7)
    const int srow = tid >> 4;
    const int chunkg = (tid & 15) ^ (srow & 7);
    const int swz = (l16 & 7);               // read-side swizzle

    for (int it = 0; it < ntiles; ++it) {
        const int c0 = it * 128;
        __syncthreads();
#pragma unroll
        for (int r = 0; r < 8; r++) {
            async_ld16(kbp + (size_t)(c0 + r * 16 + srow) * DKk + chunkg * 8,
                       Ks + ((r * 256 + tid) << 3));
            async_ld16(vbp + (size_t)(r * 16 + srow) * Ss + c0 + chunkg * 8,
                       Vs + ((r * 256 + tid) << 3));
        }
        __syncthreads();

        const int kvmax = min(127, qw0 + 31 - c0);
        const int lim_n = (kvmax >> 4) + 1;     // always even: 2,4,6,8
        const int lim_k = lim_n >> 1;

        // ---- S^T = K Q^T  (pre-scaled) ----
        floatx4 sf[8][2];
#pragma unroll
        for (int n = 0; n < 8; n++) {
            if (n < lim_n) {
                short8 kf[4];
#pragma unroll
                for (int kk = 0; kk < 4; kk++)
                    kf[kk] = *(const short8*)(Ks + (n * 16 + l16) * 128 + (((kk * 4 + quad) ^ swz) * 8));
                sf[n][0] = (floatx4){0.f, 0.f, 0.f, 0.f};
                sf[n][1] = (floatx4){0.f, 0.f, 0.f, 0.f};
#pragma unroll
                for (int kk = 0; kk < 4; kk++) {
                    sf[n][0] = __builtin_amdgcn_mfma_f32_16x16x32_bf16(kf[kk], qB[0][kk], sf[n][0], 0, 0, 0);
                    sf[n][1] = __builtin_amdgcn_mfma_f32_16x16x32_bf16(kf[kk], qB[1][kk], sf[n][1], 0, 0, 0);
                }
            }
        }

        // ---- online softmax (base-2; state per l16 lane) ----
        unsigned int pp01[8][2], pp23[8][2];
#pragma unroll
        for (int qf = 0; qf < 2; qf++) {
            const int qrow = qw0 + qf * 16 + l16;
            float mx = -__builtin_inff();
#pragma unroll
            for (int n = 0; n < 8; n++) {
                if (n < lim_n) {
                    const int kvb = c0 + n * 16 + quad * 4;
#pragma unroll
                    for (int r = 0; r < 4; r++) {
                        float v = sf[n][qf][r];
                        v = (kvb + r > qrow) ? -__builtin_inff() : v;
                        sf[n][qf][r] = v;
                        mx = fmaxf(mx, v);
                    }
                }
            }
            mx = fmaxf(mx, __shfl_xor(mx, 16, 64));
            mx = fmaxf(mx, __shfl_xor(mx, 32, 64));
            const float mnew = fmaxf(m_i[qf], mx);
            const float alpha = __builtin_amdgcn_exp2f(m_i[qf] - mnew);
            m_i[qf] = mnew;
            float rs = 0.f;
#pragma unroll
            for (int n = 0; n < 8; n++) {
                if (n < lim_n) {
                    float p0 = __builtin_amdgcn_exp2f(sf[n][qf][0] - mnew);
                    float p1 = __builtin_amdgcn_exp2f(sf[n][qf][1] - mnew);
                    float p2 = __builtin_amdgcn_exp2f(sf[n][qf][2] - mnew);
                    float p3 = __builtin_amdgcn_exp2f(sf[n][qf][3] - mnew);
                    rs += (p0 + p1) + (p2 + p3);
                    pp01[n][qf] = pk2(p0, p1);
                    pp23[n][qf] = pk2(p2, p3);
                }
            }
            rs += __shfl_xor(rs, 16, 64);
            rs += __shfl_xor(rs, 32, 64);
            l_i[qf] = l_i[qf] * alpha + rs;
#pragma unroll
            for (int md = 0; md < 8; md++)
#pragma unroll
                for (int r = 0; r < 4; r++) oacc[md][qf][r] *= alpha;
        }

        // ---- O^T += V^T P^T ----
        const int srcA = ((quad & 1) * 2) * 16 + l16;   // j<4 source lane
        const int srcB = srcA + 16;                      // j>=4 source lane
#pragma unroll
        for (int kv = 0; kv < 4; kv++) {
            if (kv < lim_k) {
                short8 pB[2];
#pragma unroll
                for (int qf = 0; qf < 2; qf++) {
                    unsigned int a01 = (unsigned int)__shfl((int)pp01[2 * kv][qf], srcA, 64);
                    unsigned int a23 = (unsigned int)__shfl((int)pp23[2 * kv][qf], srcA, 64);
                    unsigned int a45 = (unsigned int)__shfl((int)pp01[2 * kv][qf], srcB, 64);
                    unsigned int a67 = (unsigned int)__shfl((int)pp23[2 * kv][qf], srcB, 64);
                    unsigned int b01 = (unsigned int)__shfl((int)pp01[2 * kv + 1][qf], srcA, 64);
                    unsigned int b23 = (unsigned int)__shfl((int)pp23[2 * kv + 1][qf], srcA, 64);
                    unsigned int b45 = (unsigned int)__shfl((int)pp01[2 * kv + 1][qf], srcB, 64);
                    unsigned int b67 = (unsigned int)__shfl((int)pp23[2 * kv + 1][qf], srcB, 64);
                    const bool hi = quad >= 2;
                    unsigned int e[4];
                    e[0] = hi ? b01 : a01;
                    e[1] = hi ? b23 : a23;
                    e[2] = hi ? b45 : a45;
                    e[3] = hi ? b67 : a67;
                    __builtin_memcpy(&pB[qf], e, 16);
                }
#pragma unroll
                for (int md = 0; md < 8; md++) {
                    short8 vf = *(const short8*)(Vs + (md * 16 + l16) * 128 + (((kv * 4 + quad) ^ swz) * 8));
                    oacc[md][0] = __builtin_amdgcn_mfma_f32_16x16x32_bf16(vf, pB[0], oacc[md][0], 0, 0, 0);
                    oacc[md][1] = __builtin_amdgcn_mfma_f32_16x16x32_bf16(vf, pB[1], oacc[md][1], 0, 0, 0);
                }
            }
        }
    }

    // ---- epilogue: O^T (d=md*16+quad*4+r, s=qw0+qf*16+l16) -> [B,S,D] bf16 ----
    const int b = bh >> 4, h = bh & 15;
#pragma unroll
    for (int qf = 0; qf < 2; qf++) {
        const float inv = 1.0f / l_i[qf];
        const int s = qw0 + qf * 16 + l16;
        bf16* orow = o + (size_t)(b * Ss + s) * Dd + h * 128;
#pragma unroll
        for (int md = 0; md < 8; md++) {
            unsigned int w[2];
            w[0] = pk2(oacc[md][qf][0] * inv, oacc[md][qf][1] * inv);
            w[1] = pk2(oacc[md][qf][2] * inv, oacc[md][qf][3] * inv);
            __builtin_memcpy(orow + md * 16 + quad * 4, w, 8);
        }
    }
}

extern "C" void kernel_launch(void* const* d_in, const int* in_sizes, int n_in,
                              void* d_out, int out_size, void* d_ws, size_t ws_size,
                              hipStream_t stream) {
    const float* x     = (const float*)d_in[0];
    const float* w_qkv = (const float*)d_in[1];
    const float* w_out = (const float*)d_in[2];
    float* out = (float*)d_out;
    char* ws = (char*)d_ws;

    bf16*   xb  = (bf16*)(ws);                 // 32 MiB  x bf16; reused as attn output
    bf16*   wqb = (bf16*)(ws + 33554432);      // 24 MiB  w_qkv bf16
    bf16*   wob = (bf16*)(ws + 58720256);      //  8 MiB  w_out bf16
    bf16*   qb  = (bf16*)(ws + 67108864);      // 32 MiB  q   [B,H,S,dk] (pre-scaled)
    bf16*   kb  = (bf16*)(ws + 100663296);     // 32 MiB  k   [B,H,S,dk]
    bf16*   vtb = (bf16*)(ws + 134217728);     // 32 MiB  v^T [B,H,dk,S]
    float2* rt  = (float2*)(ws + 167772160);   //  1 MiB  rope tables

    cvt_bf16<<<8192, 256, 0, stream>>>(x, xb, 2097152);
    cvt_bf16<<<6144, 256, 0, stream>>>(w_qkv, wqb, 1572864);
    cvt_bf16<<<2048, 256, 0, stream>>>(w_out, wob, 524288);
    rope_tables<<<512, 256, 0, stream>>>(rt);

    gemm_bf16<1><<<dim3(48, 64), 256, 0, stream>>>(xb, wqb, 6144, 2048,
                                                   nullptr, qb, kb, vtb, rt);
    flash_attn<<<dim3(16, 64), 256, 0, stream>>>(qb, kb, vtb, xb);
    gemm_bf16<0><<<dim3(16, 64), 256, 0, stream>>>(xb, wob, 2048, 2048,
                                                   out, nullptr, nullptr, nullptr, rt);
}

// Round 4
// 553.427 us; speedup vs baseline: 2.0473x; 1.2322x over previous
//
#include <hip/hip_runtime.h>
#include <hip/hip_bf16.h>
#include <math.h>

typedef __hip_bfloat16 bf16;
typedef __attribute__((ext_vector_type(8))) short short8;   // 8 bf16 = one MFMA A/B frag
typedef __attribute__((ext_vector_type(4))) float floatx4;  // MFMA C/D frag

constexpr int Bb = 4, Ss = 2048, Dd = 2048, Hh = 16, DKk = 128;

__device__ __forceinline__ void async_ld16(const bf16* g, bf16* l) {
    __builtin_amdgcn_global_load_lds(
        (__attribute__((address_space(1))) void*)g,
        (__attribute__((address_space(3))) void*)l, 16, 0, 0);
}

__device__ __forceinline__ unsigned int pk2(float a, float b) {
    bf16 ha = __float2bfloat16(a), hb = __float2bfloat16(b);
    unsigned short ua, ub;
    __builtin_memcpy(&ua, &ha, 2);
    __builtin_memcpy(&ub, &hb, 2);
    return (unsigned int)ua | ((unsigned int)ub << 16);
}

// ------- fused prep: fp32->bf16 for x / w_qkv / w_out + RoPE tables -------
__global__ void prep(const float* __restrict__ x, const float* __restrict__ wq,
                     const float* __restrict__ wo,
                     bf16* __restrict__ xb, bf16* __restrict__ wqb,
                     bf16* __restrict__ wob, float2* __restrict__ rt) {
    const int gb = blockIdx.x;
    if (gb < 16384) {
        const float* in; bf16* out; int i;
        if (gb < 8192)       { in = x;  out = xb;  i = gb * 256 + threadIdx.x; }
        else if (gb < 14336) { in = wq; out = wqb; i = (gb - 8192) * 256 + threadIdx.x; }
        else                 { in = wo; out = wob; i = (gb - 14336) * 256 + threadIdx.x; }
        const float4* p = (const float4*)in + 2 * (size_t)i;
        float4 a = p[0], b = p[1];
        float v[8] = {a.x, a.y, a.z, a.w, b.x, b.y, b.z, b.w};
        bf16 h[8];
#pragma unroll
        for (int j = 0; j < 8; j++) h[j] = __float2bfloat16(v[j]);
        __builtin_memcpy(out + 8 * (size_t)i, h, 16);
    } else {
        int i = (gb - 16384) * 256 + threadIdx.x;   // S*64 entries
        int s = i >> 6, f = i & 63;
        float inv_freq = powf(10000.0f, -(float)(2 * f) / 128.0f);
        float ang = (float)s * inv_freq;
        rt[i] = make_float2(cosf(ang), sinf(ang));
    }
}

// ---------------- bf16 GEMM: C[M,N] = A[M,K] * B[N,K]^T ----------------
// BK=64; LDS rows are 128 B (8 x 16-B chunks) with XOR-8 swizzle applied at
// the DMA SOURCE so the global_load_lds destination stays linear.
template <int EPI>
__global__ __launch_bounds__(256, 2)
void gemm_bf16(const bf16* __restrict__ A, const bf16* __restrict__ Bm,
               int N, int K,
               float* __restrict__ outF,
               bf16* __restrict__ qb, bf16* __restrict__ kb, bf16* __restrict__ vtb,
               const float2* __restrict__ rope) {
    __shared__ bf16 As[128 * 64];   // 16 KB
    __shared__ bf16 Bs[128 * 64];   // 16 KB
    const int tid = threadIdx.x;
    const int wave = tid >> 6, lane = tid & 63;
    const int quad = lane >> 4, l16 = lane & 15;
    const int wm = wave >> 1, wn = wave & 1;
    const int m0 = blockIdx.y * 128;
    const int n0 = blockIdx.x * 128;

    const int srow = tid >> 3;                      // 0..31
    const int schunk = (tid & 7) ^ (srow & 7);      // swizzled source chunk
    const bf16* apr[4];
    const bf16* bpr[4];
#pragma unroll
    for (int r = 0; r < 4; r++) {
        apr[r] = A  + (size_t)(m0 + r * 32 + srow) * K + schunk * 8;
        bpr[r] = Bm + (size_t)(n0 + r * 32 + srow) * K + schunk * 8;
    }
    bf16* asd = As + tid * 8;
    bf16* bsd = Bs + tid * 8;

    floatx4 acc[4][4] = {};
    const int swz = l16 & 7;

    for (int k0 = 0; k0 < K; k0 += 64) {
        __syncthreads();
#pragma unroll
        for (int r = 0; r < 4; r++) {
            async_ld16(apr[r] + k0, asd + r * 2048);
            async_ld16(bpr[r] + k0, bsd + r * 2048);
        }
        __syncthreads();
#pragma unroll
        for (int kk = 0; kk < 2; kk++) {
            short8 af[4], bfr[4];
#pragma unroll
            for (int i = 0; i < 4; i++)
                af[i] = *(const short8*)(As + (wm * 64 + i * 16 + l16) * 64 + (((kk * 4 + quad) ^ swz) * 8));
#pragma unroll
            for (int j = 0; j < 4; j++)
                bfr[j] = *(const short8*)(Bs + (wn * 64 + j * 16 + l16) * 64 + (((kk * 4 + quad) ^ swz) * 8));
#pragma unroll
            for (int i = 0; i < 4; i++)
#pragma unroll
                for (int j = 0; j < 4; j++)
                    acc[i][j] = __builtin_amdgcn_mfma_f32_16x16x32_bf16(af[i], bfr[j], acc[i][j], 0, 0, 0);
        }
    }

    if (EPI == 0) {
#pragma unroll
        for (int i = 0; i < 4; i++) {
            const int gm0 = m0 + wm * 64 + i * 16 + quad * 4;
#pragma unroll
            for (int j = 0; j < 4; j++) {
                const int gn = n0 + wn * 64 + j * 16 + l16;
#pragma unroll
                for (int r = 0; r < 4; r++)
                    outF[(size_t)(gm0 + r) * N + gn] = acc[i][j][r];
            }
        }
    } else {
        const int t = n0 >> 11;          // 0=q 1=k 2=v
        const int h = (n0 >> 7) & 15;
        const float qscale = 0.08838834764831845f * 1.442695040888963f;
        if (t < 2) {
#pragma unroll
            for (int j = 0; j < 4; j++) {
                const int d = wn * 64 + j * 16 + l16;
#pragma unroll
                for (int i = 0; i < 4; i++) {
#pragma unroll
                    for (int r = 0; r < 4; r++) {
                        const int gm = m0 + wm * 64 + i * 16 + quad * 4 + r;
                        const int b = gm >> 11, s = gm & 2047;
                        const size_t bh = (size_t)(b * Hh + h);
                        float val = acc[i][j][r];
                        float partner = __shfl_xor(val, 1, 64);
                        float2 cs = rope[s * 64 + (d >> 1)];
                        float nv = (d & 1) ? (val * cs.x + partner * cs.y)
                                           : (val * cs.x - partner * cs.y);
                        if (t == 0) {
                            qb[(bh * Ss + s) * DKk + d] = __float2bfloat16(nv * qscale);
                        } else {
                            kb[(bh * Ss + s) * DKk + d] = __float2bfloat16(nv);
                        }
                    }
                }
            }
        } else {
#pragma unroll
            for (int j = 0; j < 4; j++) {
                const int d = wn * 64 + j * 16 + l16;
#pragma unroll
                for (int i = 0; i < 4; i++) {
                    const int gm = m0 + wm * 64 + i * 16 + quad * 4;
                    const int b = gm >> 11, s = gm & 2047;
                    const size_t bh = (size_t)(b * Hh + h);
                    unsigned int w[2];
                    w[0] = pk2(acc[i][j][0], acc[i][j][1]);
                    w[1] = pk2(acc[i][j][2], acc[i][j][3]);
                    __builtin_memcpy(vtb + (bh * DKk + d) * Ss + s, w, 8);
                }
            }
        }
    }
}

// ---------------- flash attention tile body (full vs diagonal) ------------
template <bool DIAG>
__device__ __forceinline__ void attn_tile(
    int c0, int qw0,
    const bf16* __restrict__ kbp, const bf16* __restrict__ vbp,
    bf16* Ks, bf16* Vs,
    const short8 (&qB)[2][4],
    floatx4 (&oacc)[8][2], float (&m_i)[2], float (&l_i)[2],
    int tid, int wave, int quad, int l16, int srow, int chunkg, int swz)
{
    __syncthreads();
#pragma unroll
    for (int r = 0; r < 8; r++) {
        async_ld16(kbp + (size_t)(c0 + r * 16 + srow) * DKk + chunkg * 8,
                   Ks + ((r * 256 + tid) << 3));
        async_ld16(vbp + (size_t)(r * 16 + srow) * Ss + c0 + chunkg * 8,
                   Vs + ((r * 256 + tid) << 3));
    }
    __syncthreads();

    const int lim_n = DIAG ? (wave * 2 + 2) : 8;
    const int lim_k = DIAG ? (wave + 1) : 4;

    // ---- S^T = K Q^T  (q pre-scaled by 1/sqrt(dk)*log2 e) ----
    floatx4 sf[8][2];
#pragma unroll
    for (int n = 0; n < 8; n++) {
        if (n < lim_n) {
            short8 kf[4];
#pragma unroll
            for (int kk = 0; kk < 4; kk++)
                kf[kk] = *(const short8*)(Ks + (n * 16 + l16) * 128 + (((kk * 4 + quad) ^ swz) * 8));
            sf[n][0] = (floatx4){0.f, 0.f, 0.f, 0.f};
            sf[n][1] = (floatx4){0.f, 0.f, 0.f, 0.f};
#pragma unroll
            for (int kk = 0; kk < 4; kk++) {
                sf[n][0] = __builtin_amdgcn_mfma_f32_16x16x32_bf16(kf[kk], qB[0][kk], sf[n][0], 0, 0, 0);
                sf[n][1] = __builtin_amdgcn_mfma_f32_16x16x32_bf16(kf[kk], qB[1][kk], sf[n][1], 0, 0, 0);
            }
        }
    }

    // ---- online softmax (base-2; state per l16 lane, replicated in quads) ----
    unsigned int pp01[8][2], pp23[8][2];
#pragma unroll
    for (int qf = 0; qf < 2; qf++) {
        float mx = -__builtin_inff();
        if (DIAG) {
            const int qrow = qw0 + qf * 16 + l16;
#pragma unroll
            for (int n = 0; n < 8; n++) {
                if (n < lim_n) {
                    const int kvb = c0 + n * 16 + quad * 4;
#pragma unroll
                    for (int r = 0; r < 4; r++) {
                        float v = sf[n][qf][r];
                        v = (kvb + r > qrow) ? -__builtin_inff() : v;
                        sf[n][qf][r] = v;
                        mx = fmaxf(mx, v);
                    }
                }
            }
        } else {
#pragma unroll
            for (int n = 0; n < 8; n++)
#pragma unroll
                for (int r = 0; r < 4; r++) mx = fmaxf(mx, sf[n][qf][r]);
        }
        mx = fmaxf(mx, __shfl_xor(mx, 16, 64));
        mx = fmaxf(mx, __shfl_xor(mx, 32, 64));
        const float mnew = fmaxf(m_i[qf], mx);
        const float alpha = __builtin_amdgcn_exp2f(m_i[qf] - mnew);
        m_i[qf] = mnew;
        float rs = 0.f;
#pragma unroll
        for (int n = 0; n < 8; n++) {
            if (n < lim_n) {
                float p0 = __builtin_amdgcn_exp2f(sf[n][qf][0] - mnew);
                float p1 = __builtin_amdgcn_exp2f(sf[n][qf][1] - mnew);
                float p2 = __builtin_amdgcn_exp2f(sf[n][qf][2] - mnew);
                float p3 = __builtin_amdgcn_exp2f(sf[n][qf][3] - mnew);
                rs += (p0 + p1) + (p2 + p3);
                pp01[n][qf] = pk2(p0, p1);
                pp23[n][qf] = pk2(p2, p3);
            }
        }
        rs += __shfl_xor(rs, 16, 64);
        rs += __shfl_xor(rs, 32, 64);
        l_i[qf] = l_i[qf] * alpha + rs;
#pragma unroll
        for (int md = 0; md < 8; md++)
#pragma unroll
            for (int r = 0; r < 4; r++) oacc[md][qf][r] *= alpha;
    }

    // ---- O^T += V^T P^T  (P^T B-frags built in-register via shuffles) ----
    const int srcA = ((quad & 1) * 2) * 16 + l16;
    const int srcB = srcA + 16;
#pragma unroll
    for (int kv = 0; kv < 4; kv++) {
        if (kv < lim_k) {
            short8 pB[2];
#pragma unroll
            for (int qf = 0; qf < 2; qf++) {
                unsigned int a01 = (unsigned int)__shfl((int)pp01[2 * kv][qf], srcA, 64);
                unsigned int a23 = (unsigned int)__shfl((int)pp23[2 * kv][qf], srcA, 64);
                unsigned int a45 = (unsigned int)__shfl((int)pp01[2 * kv][qf], srcB, 64);
                unsigned int a67 = (unsigned int)__shfl((int)pp23[2 * kv][qf], srcB, 64);
                unsigned int b01 = (unsigned int)__shfl((int)pp01[2 * kv + 1][qf], srcA, 64);
                unsigned int b23 = (unsigned int)__shfl((int)pp23[2 * kv + 1][qf], srcA, 64);
                unsigned int b45 = (unsigned int)__shfl((int)pp01[2 * kv + 1][qf], srcB, 64);
                unsigned int b67 = (unsigned int)__shfl((int)pp23[2 * kv + 1][qf], srcB, 64);
                const bool hi = quad >= 2;
                unsigned int e[4];
                e[0] = hi ? b01 : a01;
                e[1] = hi ? b23 : a23;
                e[2] = hi ? b45 : a45;
                e[3] = hi ? b67 : a67;
                __builtin_memcpy(&pB[qf], e, 16);
            }
#pragma unroll
            for (int md = 0; md < 8; md++) {
                short8 vf = *(const short8*)(Vs + (md * 16 + l16) * 128 + (((kv * 4 + quad) ^ swz) * 8));
                oacc[md][0] = __builtin_amdgcn_mfma_f32_16x16x32_bf16(vf, pB[0], oacc[md][0], 0, 0, 0);
                oacc[md][1] = __builtin_amdgcn_mfma_f32_16x16x32_bf16(vf, pB[1], oacc[md][1], 0, 0, 0);
            }
        }
    }
}

// ---------------- flash attention (balanced q-tile pairing) ----------------
// grid (8, B*H): block xp processes q-tiles {15-xp, xp} sequentially ->
// every block does exactly 17 tile-units; 512 blocks = exactly 2/CU, no tail.
__global__ __launch_bounds__(256, 2)
void flash_attn(const bf16* __restrict__ q, const bf16* __restrict__ k,
                const bf16* __restrict__ vt, bf16* __restrict__ o) {
    __shared__ bf16 Ks[128 * 128];   // 32 KB  rows=kv, cols=d
    __shared__ bf16 Vs[128 * 128];   // 32 KB  rows=d,  cols=kv
    const int tid = threadIdx.x, wave = tid >> 6, lane = tid & 63;
    const int quad = lane >> 4, l16 = lane & 15;
    const int bh = blockIdx.y;
    const int xp = blockIdx.x;       // 0..7
    const bf16* qbp = q  + (size_t)bh * Ss * DKk;
    const bf16* kbp = k  + (size_t)bh * Ss * DKk;
    const bf16* vbp = vt + (size_t)bh * DKk * Ss;
    const int b = bh >> 4, h = bh & 15;

    const int srow = tid >> 4;
    const int chunkg = (tid & 15) ^ (srow & 7);
    const int swz = (l16 & 7);

    for (int pass = 0; pass < 2; ++pass) {
        const int xq = pass ? xp : 15 - xp;
        const int qw0 = xq * 128 + wave * 32;

        short8 qB[2][4];
#pragma unroll
        for (int qf = 0; qf < 2; qf++)
#pragma unroll
            for (int kk = 0; kk < 4; kk++)
                qB[qf][kk] = *(const short8*)(qbp + (size_t)(qw0 + qf * 16 + l16) * DKk + kk * 32 + quad * 8);

        floatx4 oacc[8][2] = {};
        float m_i[2] = {-__builtin_inff(), -__builtin_inff()};
        float l_i[2] = {0.f, 0.f};

        for (int it = 0; it < xq; ++it)
            attn_tile<false>(it * 128, qw0, kbp, vbp, Ks, Vs, qB, oacc, m_i, l_i,
                             tid, wave, quad, l16, srow, chunkg, swz);
        attn_tile<true>(xq * 128, qw0, kbp, vbp, Ks, Vs, qB, oacc, m_i, l_i,
                        tid, wave, quad, l16, srow, chunkg, swz);

#pragma unroll
        for (int qf = 0; qf < 2; qf++) {
            const float inv = 1.0f / l_i[qf];
            const int s = qw0 + qf * 16 + l16;
            bf16* orow = o + (size_t)(b * Ss + s) * Dd + h * 128;
#pragma unroll
            for (int md = 0; md < 8; md++) {
                unsigned int w[2];
                w[0] = pk2(oacc[md][qf][0] * inv, oacc[md][qf][1] * inv);
                w[1] = pk2(oacc[md][qf][2] * inv, oacc[md][qf][3] * inv);
                __builtin_memcpy(orow + md * 16 + quad * 4, w, 8);
            }
        }
    }
}

extern "C" void kernel_launch(void* const* d_in, const int* in_sizes, int n_in,
                              void* d_out, int out_size, void* d_ws, size_t ws_size,
                              hipStream_t stream) {
    const float* x     = (const float*)d_in[0];
    const float* w_qkv = (const float*)d_in[1];
    const float* w_out = (const float*)d_in[2];
    float* out = (float*)d_out;
    char* ws = (char*)d_ws;

    bf16*   xb  = (bf16*)(ws);                 // 32 MiB  x bf16; reused as attn output
    bf16*   wqb = (bf16*)(ws + 33554432);      // 24 MiB  w_qkv bf16
    bf16*   wob = (bf16*)(ws + 58720256);      //  8 MiB  w_out bf16
    bf16*   qb  = (bf16*)(ws + 67108864);      // 32 MiB  q   [B,H,S,dk] (pre-scaled)
    bf16*   kb  = (bf16*)(ws + 100663296);     // 32 MiB  k   [B,H,S,dk]
    bf16*   vtb = (bf16*)(ws + 134217728);     // 32 MiB  v^T [B,H,dk,S]
    float2* rt  = (float2*)(ws + 167772160);   //  1 MiB  rope tables

    prep<<<16896, 256, 0, stream>>>(x, w_qkv, w_out, xb, wqb, wob, rt);

    gemm_bf16<1><<<dim3(48, 64), 256, 0, stream>>>(xb, wqb, 6144, 2048,
                                                   nullptr, qb, kb, vtb, rt);
    flash_attn<<<dim3(8, 64), 256, 0, stream>>>(qb, kb, vtb, xb);
    gemm_bf16<0><<<dim3(16, 64), 256, 0, stream>>>(xb, wob, 2048, 2048,
                                                   out, nullptr, nullptr, nullptr, rt);
}